// Round 1
// baseline (16357.822 us; speedup 1.0000x reference)
//
#include <hip/hip_runtime.h>

#define T_STEPS 32768
#define DIN 256
#define HID 64
#define G3 192
#define JJ 1024
#define CHUNK 32

// ---------------- K1: gi = x @ w_ih^T + b_ih  (T x 192) ----------------
__global__ __launch_bounds__(192)
void k_gi(const float* __restrict__ states, const float* __restrict__ w_ih,
          const float* __restrict__ b_ih, float* __restrict__ gi)
{
    __shared__ __align__(16) float xs[32 * DIN];   // 32 KB x-tile
    const int tid  = threadIdx.x;
    const int row0 = blockIdx.x * 32;

    for (int i = tid; i < 32 * DIN; i += 192)
        xs[i] = states[(size_t)(row0 + (i >> 8)) * (DIN + 3) + (i & 255)];
    __syncthreads();

    const int c = tid;                 // one output column per thread
    float acc[32];
#pragma unroll
    for (int r = 0; r < 32; ++r) acc[r] = 0.f;

    for (int k4 = 0; k4 < DIN / 4; ++k4) {
        const float4 wv = *(const float4*)&w_ih[c * DIN + k4 * 4];
#pragma unroll
        for (int r = 0; r < 32; ++r) {
            const float4 xv = *(const float4*)&xs[r * DIN + k4 * 4];  // LDS broadcast
            acc[r] += xv.x * wv.x + xv.y * wv.y + xv.z * wv.z + xv.w * wv.w;
        }
    }
    const float bi = b_ih[c];
#pragma unroll
    for (int r = 0; r < 32; ++r)
        gi[(size_t)(row0 + r) * G3 + c] = acc[r] + bi;
}

// ---------------- K2: sequential GRU scan (single workgroup) ----------------
__global__ __launch_bounds__(192, 1)
void k_scan(const float* __restrict__ gi, const float* __restrict__ w_hh,
            const float* __restrict__ b_hh, const float* __restrict__ h0,
            float* __restrict__ hs, float* __restrict__ h_final)
{
    __shared__ __align__(16) float gi_buf[2][CHUNK * G3]; // 48 KB double buffer
    __shared__ __align__(16) float hs_buf[CHUNK * HID];   // 8 KB h history staging
    __shared__ __align__(16) float h_lds[HID];
    __shared__ float sz[HID];   // z pre-activation
    __shared__ float an[HID];   // recurrent part of n gate (W_n h + b_hn)

    const int tid = threadIdx.x;

    // each thread caches its w_hh row in registers (64 VGPRs)
    float w[HID];
#pragma unroll
    for (int k = 0; k < HID; ++k) w[k] = w_hh[tid * HID + k];
    const float bh = b_hh[tid];

    if (tid < HID) h_lds[tid] = h0[tid];
    for (int i = tid; i < CHUNK * G3; i += G3)   // preload chunk 0
        gi_buf[0][i] = gi[i];
    __syncthreads();

    const int nch = T_STEPS / CHUNK;
    for (int ch = 0; ch < nch; ++ch) {
        const int cur = ch & 1;

        // Prefetch next gi chunk into the other LDS buffer.
        // (Loads+stores complete here; keeps vmcnt clean across step barriers.)
        if (ch + 1 < nch) {
            const float* src = gi + (size_t)(ch + 1) * CHUNK * G3;
            float* dst = gi_buf[cur ^ 1];
#pragma unroll
            for (int i = 0; i < (CHUNK * G3) / (G3 * 4); ++i) {   // 8 float4 per thread
                const float4 v = *(const float4*)&src[(tid + i * G3) * 4];
                *(float4*)&dst[(tid + i * G3) * 4] = v;
            }
        }

#pragma unroll 1
        for (int s = 0; s < CHUNK; ++s) {
            // load h into registers: 16 broadcast ds_read_b128
            float hreg[HID];
#pragma unroll
            for (int k = 0; k < HID; k += 4)
                *(float4*)&hreg[k] = *(const float4*)&h_lds[k];

            float acc = bh;
#pragma unroll
            for (int k = 0; k < HID; ++k) acc += w[k] * hreg[k];

            const float giv = gi_buf[cur][s * G3 + tid];
            if (tid >= 128)      an[tid - 128] = acc;        // wave 2: recurrent n
            else if (tid >= 64)  sz[tid - 64]  = acc + giv;  // wave 1: z preact
            __syncthreads();

            if (tid < HID) {                                 // wave 0: gates
                const float r  = 1.f / (1.f + __expf(-(acc + giv)));
                const float z  = 1.f / (1.f + __expf(-sz[tid]));
                const float gn = gi_buf[cur][s * G3 + 128 + tid];
                const float npre = gn + r * an[tid];
                const float n  = 1.f - 2.f / (__expf(2.f * npre) + 1.f);  // tanh
                const float hp = h_lds[tid];
                const float hn = (1.f - z) * n + z * hp;
                h_lds[tid] = hn;
                hs_buf[s * HID + tid] = hn;
            }
            __syncthreads();
        }

        // flush staged h history once per chunk (one store-drain per 32 steps)
        float* dsth = hs + (size_t)ch * CHUNK * HID;
        for (int i = tid; i < CHUNK * HID; i += G3)
            dsth[i] = hs_buf[i];
    }

    if (tid < HID) h_final[tid] = h_lds[tid];
}

// ---------------- K3: logits = hs @ w_out^T + b_out, masked ----------------
__global__ __launch_bounds__(256)
void k_out(const float* __restrict__ hs, const float* __restrict__ w_out,
           const float* __restrict__ b_out, const int* __restrict__ mask,
           float* __restrict__ out)
{
    __shared__ __align__(16) float hs_s[16 * HID];
    const int tid  = threadIdx.x;
    const int row0 = blockIdx.x * 16;

    {   // stage 16 rows of hs (contiguous 1024 floats)
        const float4 v = *(const float4*)&hs[(size_t)row0 * HID + tid * 4];
        *(float4*)&hs_s[tid * 4] = v;
    }
    __syncthreads();

    float acc[16][4];
#pragma unroll
    for (int r = 0; r < 16; ++r)
#pragma unroll
        for (int cc = 0; cc < 4; ++cc) acc[r][cc] = 0.f;

    for (int k4 = 0; k4 < HID / 4; ++k4) {
        float4 wv[4];
#pragma unroll
        for (int cc = 0; cc < 4; ++cc)
            wv[cc] = *(const float4*)&w_out[(size_t)(cc * 256 + tid) * HID + k4 * 4];
#pragma unroll
        for (int r = 0; r < 16; ++r) {
            const float4 hv = *(const float4*)&hs_s[r * HID + k4 * 4];  // broadcast
#pragma unroll
            for (int cc = 0; cc < 4; ++cc)
                acc[r][cc] += hv.x * wv[cc].x + hv.y * wv[cc].y +
                              hv.z * wv[cc].z + hv.w * wv[cc].w;
        }
    }

#pragma unroll
    for (int cc = 0; cc < 4; ++cc) {
        const int c = cc * 256 + tid;
        const float bo = b_out[c];
        const int m = mask[c];
#pragma unroll
        for (int r = 0; r < 16; ++r) {
            const float v = (m == 0) ? -1e9f : (acc[r][cc] + bo);
            out[(size_t)(row0 + r) * JJ + c] = v;
        }
    }
}

// ---------------- launch ----------------
extern "C" void kernel_launch(void* const* d_in, const int* in_sizes, int n_in,
                              void* d_out, int out_size, void* d_ws, size_t ws_size,
                              hipStream_t stream)
{
    const float* states = (const float*)d_in[0];
    const float* h0     = (const float*)d_in[1];
    const float* w_ih   = (const float*)d_in[2];
    const float* w_hh   = (const float*)d_in[3];
    const float* b_ih   = (const float*)d_in[4];
    const float* b_hh   = (const float*)d_in[5];
    const float* w_out  = (const float*)d_in[6];
    const float* b_out  = (const float*)d_in[7];
    const int*   mask   = (const int*)d_in[8];

    float* out = (float*)d_out;
    float* gi  = (float*)d_ws;                         // T*192 fp32 = 25.2 MB
    float* hs  = gi + (size_t)T_STEPS * G3;            // T*64  fp32 =  8.4 MB
    float* h_final = out + (size_t)T_STEPS * JJ;       // after logits

    k_gi  <<<dim3(T_STEPS / 32), dim3(192), 0, stream>>>(states, w_ih, b_ih, gi);
    k_scan<<<dim3(1),            dim3(192), 0, stream>>>(gi, w_hh, b_hh, h0, hs, h_final);
    k_out <<<dim3(T_STEPS / 16), dim3(256), 0, stream>>>(hs, w_out, b_out, mask, out);
}